// Round 8
// baseline (290.583 us; speedup 1.0000x reference)
//
#include <hip/hip_runtime.h>
#include <math.h>

// CantorAttention: B=2, S=2048, DIM=512, H=8, HD=64, K=64
#define B_    2
#define S_    2048
#define DIM_  512
#define H_    8
#define HD_   64
#define K_    64
#define M_    (B_ * S_)          // 4096
#define NQKV_ (3 * DIM_)         // 1536
#define NBLK_ 256                // 256 blocks <= 256 CUs -> co-resident at any occupancy

typedef __attribute__((ext_vector_type(8))) _Float16       half8;
typedef __attribute__((ext_vector_type(8))) unsigned short ushort8v;
typedef __attribute__((ext_vector_type(4))) float          float4v;

union H8 { half8 h; ushort8v u; unsigned int w[4]; };

__device__ __forceinline__ unsigned short f2h(float f) {
    _Float16 h = (_Float16)f;
    unsigned short u; __builtin_memcpy(&u, &h, 2); return u;
}
__device__ __forceinline__ unsigned int pkrtz(float a, float b) {
    auto r = __builtin_amdgcn_cvt_pkrtz(a, b);   // __fp16x2: D.lo=a, D.hi=b
    unsigned int u; __builtin_memcpy(&u, &r, 4); return u;
}
__device__ __forceinline__ void load_lds16(const unsigned short* g, unsigned short* l) {
    __builtin_amdgcn_global_load_lds(
        (const __attribute__((address_space(1))) void*)g,
        (__attribute__((address_space(3))) void*)l, 16, 0, 0);
}

// ---- hardened grid barrier --------------------------------------------------
// All threads fence (drains each wave's stores at the syncthreads + agent-scope
// L2 writeback) BEFORE the arrive; release/acquire atomics at agent scope;
// all threads fence after (cache invalidate). Bounded spin: a broken barrier
// produces a wrong answer (diagnosable), never a hung container.
__device__ __forceinline__ void gbar(int* cnt, int nblk) {
    __syncthreads();
    __threadfence();
    __syncthreads();
    if (threadIdx.x == 0) {
        __hip_atomic_fetch_add(cnt, 1, __ATOMIC_RELEASE, __HIP_MEMORY_SCOPE_AGENT);
        int spins = 0;
        while (__hip_atomic_load(cnt, __ATOMIC_ACQUIRE, __HIP_MEMORY_SCOPE_AGENT) < nblk) {
            __builtin_amdgcn_s_sleep(7);
            if (++spins > (1 << 22)) break;     // ~1s bail-out
        }
    }
    __syncthreads();
    __threadfence();
}

// ===========================================================================
// gemm_tile: verified fp16 MFMA GEMM tile (rounds 5/6).
//   mode 0: fp32 C.  mode 1: qkv scatter -> Q/K/V fp16 [B,H,S,HD], SCALE in Q.
// ===========================================================================
template<int BM, int BN, int WM, int WN>
__device__ void gemm_tile(char* smemRaw,
    const unsigned short* __restrict__ Ahi, const unsigned short* __restrict__ Wh,
    const float* __restrict__ bias, float* __restrict__ C,
    unsigned short* __restrict__ Qho, unsigned short* __restrict__ Kho,
    unsigned short* __restrict__ Vho,
    int N, int Kd, int mode, int m0, int n0)
{
    constexpr int TM = WM / 16, TN = WN / 16;
    constexpr int WAVES_N = BN / WN;
    auto Ah = (unsigned short (*)[BM][32])smemRaw;
    auto Bh = (unsigned short (*)[BN][32])(smemRaw + 2 * BM * 32 * 2);

    const int t = threadIdx.x, lane = t & 63, wave = t >> 6;
    const int wm = (wave / WAVES_N) * WM, wn = (wave % WAVES_N) * WN;
    const int l15 = lane & 15, l4 = lane >> 4;
    const int srow = lane >> 2;
    const int scol = (lane & 3) * 8;

    float4v acc[TM][TN];
    #pragma unroll
    for (int i = 0; i < TM; ++i)
        #pragma unroll
        for (int j = 0; j < TN; ++j)
            #pragma unroll
            for (int r = 0; r < 4; ++r) acc[i][j][r] = 0.f;

    const int NK = Kd / 32;

    #pragma unroll
    for (int c = wave; c < BM / 16; c += 4) {
        size_t g = (size_t)(m0 + c * 16 + srow) * Kd + scol;
        load_lds16(&Ahi[g], &Ah[0][c * 16][0]);
    }
    #pragma unroll
    for (int c = wave; c < BN / 16; c += 4) {
        size_t g = (size_t)(n0 + c * 16 + srow) * Kd + scol;
        load_lds16(&Wh[g], &Bh[0][c * 16][0]);
    }
    __syncthreads();

    for (int ks = 0; ks < NK; ++ks) {
        const int cur = ks & 1, nxt = cur ^ 1;

        if (ks + 1 < NK) {
            const int k1 = (ks + 1) * 32;
            #pragma unroll
            for (int c = wave; c < BM / 16; c += 4) {
                size_t g = (size_t)(m0 + c * 16 + srow) * Kd + k1 + scol;
                load_lds16(&Ahi[g], &Ah[nxt][c * 16][0]);
            }
            #pragma unroll
            for (int c = wave; c < BN / 16; c += 4) {
                size_t g = (size_t)(n0 + c * 16 + srow) * Kd + k1 + scol;
                load_lds16(&Wh[g], &Bh[nxt][c * 16][0]);
            }
        }

        half8 fa[TM], fb[TN];
        #pragma unroll
        for (int im = 0; im < TM; ++im)
            fa[im] = *(const half8*)&Ah[cur][wm + im * 16 + l15][l4 * 8];
        #pragma unroll
        for (int in = 0; in < TN; ++in)
            fb[in] = *(const half8*)&Bh[cur][wn + in * 16 + l15][l4 * 8];
        #pragma unroll
        for (int im = 0; im < TM; ++im)
            #pragma unroll
            for (int in = 0; in < TN; ++in)
                acc[im][in] = __builtin_amdgcn_mfma_f32_16x16x32_f16(fa[im], fb[in], acc[im][in], 0, 0, 0);

        __syncthreads();
    }

    if (mode == 0) {
        #pragma unroll
        for (int in = 0; in < TN; ++in) {
            int n = n0 + wn + in * 16 + l15;
            float bv = bias[n];
            #pragma unroll
            for (int im = 0; im < TM; ++im) {
                int mb = m0 + wm + im * 16 + l4 * 4;
                #pragma unroll
                for (int r = 0; r < 4; ++r)
                    C[(size_t)(mb + r) * N + n] = acc[im][in][r] + bv;
            }
        }
    } else {
        #pragma unroll
        for (int in = 0; in < TN; ++in) {
            int n = n0 + wn + in * 16 + l15;
            int which = n >> 9, h = (n >> 6) & 7, d = n & 63;
            unsigned short* dst = (which == 0) ? Qho : (which == 1 ? Kho : Vho);
            float bv = bias[n];
            float scl = (which == 0) ? 0.125f : 1.0f;
            #pragma unroll
            for (int im = 0; im < TM; ++im) {
                int mb = m0 + wm + im * 16 + l4 * 4;
                #pragma unroll
                for (int r = 0; r < 4; ++r) {
                    int m = mb + r, b = m >> 11, s = m & 2047;
                    dst[(((size_t)b * H_ + h) * S_ + s) * HD_ + d] =
                        f2h((acc[im][in][r] + bv) * scl);
                }
            }
        }
    }
}

// ===========================================================================
// attn_one: verified MFMA class-grouped attention unit (round 5), with
// index clamps so poisoned metadata can never fault.
// ===========================================================================
__device__ void attn_one(int bh, int chunk, unsigned short* Vlds,
    const unsigned short* __restrict__ Qh, const unsigned short* __restrict__ Kh,
    const unsigned short* __restrict__ Vh, const int* __restrict__ routes,
    const int* __restrict__ members, const int4* __restrict__ recs,
    unsigned short* __restrict__ Oh)
{
    const int lane = threadIdx.x & 63;
    const int g = lane >> 4, m16 = lane & 15;
    const int b = bh >> 3, h = bh & 7;

    const unsigned short* qbase = Qh + (size_t)bh * S_ * HD_;
    const unsigned short* kbase = Kh + (size_t)bh * S_ * HD_;
    const unsigned short* vbase = Vh + (size_t)bh * S_ * HD_;

    const int4 rec = recs[chunk & 2047];
    const int leader = rec.x & 2047;
    const int mstart = rec.y & 2047;
    const int mcnt   = rec.z < 1 ? 1 : (rec.z > 16 ? 16 : rec.z);

    const int rl = routes[(size_t)leader * K_ + lane] & 2047;
    const int mm = members[(mstart + (m16 < mcnt ? m16 : mcnt - 1)) & 2047] & 2047;

    #pragma unroll
    for (int i = 0; i < 8; ++i) {
        int rv = __shfl(rl, i * 8 + (lane >> 3));
        int sc = (lane & 7) ^ i;
        load_lds16(&vbase[(size_t)rv * HD_ + sc * 8], Vlds + i * 512);
    }

    H8 ka[4][2];
    #pragma unroll
    for (int tt = 0; tt < 4; ++tt) {
        int rt = __shfl(rl, tt * 16 + m16);
        const unsigned short* kr = &kbase[(size_t)rt * HD_];
        ka[tt][0].u = *(const ushort8v*)(kr + g * 8);
        ka[tt][1].u = *(const ushort8v*)(kr + 32 + g * 8);
    }
    const unsigned short* qr = &qbase[(size_t)mm * HD_];
    H8 qb0, qb1;
    qb0.u = *(const ushort8v*)(qr + g * 8);
    qb1.u = *(const ushort8v*)(qr + 32 + g * 8);

    float4v acc[4];
    #pragma unroll
    for (int tt = 0; tt < 4; ++tt) {
        #pragma unroll
        for (int r = 0; r < 4; ++r) acc[tt][r] = 0.f;
    }
    #pragma unroll
    for (int tt = 0; tt < 4; ++tt) {
        acc[tt] = __builtin_amdgcn_mfma_f32_16x16x32_f16(ka[tt][0].h, qb0.h, acc[tt], 0, 0, 0);
        acc[tt] = __builtin_amdgcn_mfma_f32_16x16x32_f16(ka[tt][1].h, qb1.h, acc[tt], 0, 0, 0);
    }

    float mx = acc[0][0];
    #pragma unroll
    for (int tt = 0; tt < 4; ++tt)
        #pragma unroll
        for (int r = 0; r < 4; ++r) mx = fmaxf(mx, acc[tt][r]);
    mx = fmaxf(mx, __shfl_xor(mx, 16));
    mx = fmaxf(mx, __shfl_xor(mx, 32));
    float ew[4][4], su = 0.f;
    #pragma unroll
    for (int tt = 0; tt < 4; ++tt)
        #pragma unroll
        for (int r = 0; r < 4; ++r) { ew[tt][r] = __expf(acc[tt][r] - mx); su += ew[tt][r]; }
    su += __shfl_xor(su, 16);
    su += __shfl_xor(su, 32);
    const float rinv = __builtin_amdgcn_rcpf(su);

    unsigned int whu[4][2];
    #pragma unroll
    for (int tt = 0; tt < 4; ++tt) {
        whu[tt][0] = pkrtz(ew[tt][0] * rinv, ew[tt][1] * rinv);
        whu[tt][1] = pkrtz(ew[tt][2] * rinv, ew[tt][3] * rinv);
    }

    const int A0 = (((g & 1) << 5) | m16) * 4;
    const int A1 = A0 + 64;
    const bool ghi = (g >> 1) != 0;
    H8 pa[2];
    #pragma unroll
    for (int s = 0; s < 2; ++s) {
        unsigned int l0a = (unsigned int)__builtin_amdgcn_ds_bpermute(A0, (int)whu[2 * s][0]);
        unsigned int l0b = (unsigned int)__builtin_amdgcn_ds_bpermute(A0, (int)whu[2 * s + 1][0]);
        unsigned int h0a = (unsigned int)__builtin_amdgcn_ds_bpermute(A0, (int)whu[2 * s][1]);
        unsigned int h0b = (unsigned int)__builtin_amdgcn_ds_bpermute(A0, (int)whu[2 * s + 1][1]);
        unsigned int l1a = (unsigned int)__builtin_amdgcn_ds_bpermute(A1, (int)whu[2 * s][0]);
        unsigned int l1b = (unsigned int)__builtin_amdgcn_ds_bpermute(A1, (int)whu[2 * s + 1][0]);
        unsigned int h1a = (unsigned int)__builtin_amdgcn_ds_bpermute(A1, (int)whu[2 * s][1]);
        unsigned int h1b = (unsigned int)__builtin_amdgcn_ds_bpermute(A1, (int)whu[2 * s + 1][1]);
        pa[s].w[0] = ghi ? l0b : l0a;
        pa[s].w[1] = ghi ? h0b : h0a;
        pa[s].w[2] = ghi ? l1b : l1a;
        pa[s].w[3] = ghi ? h1b : h1a;
    }

    int mr[4];
    #pragma unroll
    for (int r = 0; r < 4; ++r)
        mr[r] = __builtin_amdgcn_ds_bpermute((g * 4 + r) * 4, mm) & 2047;

    asm volatile("s_waitcnt vmcnt(0)" ::: "memory");
    __builtin_amdgcn_sched_barrier(0);

    #pragma unroll
    for (int dblk = 0; dblk < 4; ++dblk) {
        H8 vb[2];
        #pragma unroll
        for (int s = 0; s < 2; ++s) {
            const char* vp = (const char*)Vlds + (s * 32 + g * 8) * 128 +
                (((dblk * 16 + m16) * 2) ^ ((((s * 4 + g) & 7)) << 4));
            #pragma unroll
            for (int j = 0; j < 8; ++j)
                vb[s].u[j] = *(const unsigned short*)(vp + j * 128);
        }
        float4v o;
        o[0] = 0.f; o[1] = 0.f; o[2] = 0.f; o[3] = 0.f;
        o = __builtin_amdgcn_mfma_f32_16x16x32_f16(pa[0].h, vb[0].h, o, 0, 0, 0);
        o = __builtin_amdgcn_mfma_f32_16x16x32_f16(pa[1].h, vb[1].h, o, 0, 0, 0);
        #pragma unroll
        for (int r = 0; r < 4; ++r) {
            if (g * 4 + r < mcnt) {
                size_t oi = ((size_t)b * S_ + mr[r]) * DIM_ + h * HD_ + dblk * 16 + m16;
                Oh[oi] = f2h(o[r]);
            }
        }
    }
}

// ===========================================================================
// zero_ws: launch #1 — zero route counters + barrier counters + nchp.
// Pure kernel (no memset API) for maximal graph-capture safety.
// ===========================================================================
__global__ __launch_bounds__(256) void zero_ws(int* gcnt, int* bar, int* nchp)
{
    int i = blockIdx.x * 256 + threadIdx.x;
    if (i < 2048) gcnt[i] = 0;
    if (i < 16) bar[i] = 0;
    if (i == 16) nchp[0] = 0;
}

// ===========================================================================
// MEGA: whole pipeline, 256 blocks x 256 threads, 3 hardened grid barriers.
//   A: x-convert + W transposes (8 units/block) + route-count
//   B: qkv GEMM (blocks 0..254) || grouping (block 255)
//   C: attention (flat chunk x 16bh list)
//   D: out-proj GEMM (2 tiles/block)
// ===========================================================================
struct MegaArgs {
    const float* x; unsigned short* xh;
    const float* Wq; unsigned short* wqh;
    const float* Wo; unsigned short* woh;
    const float* bqkv; const float* bout;
    const int* routes; int* members; int4* recs; int* nchp; int* gcnt; int* bar;
    unsigned short* Qh; unsigned short* Kh; unsigned short* Vh;
    unsigned short* ah; float* out;
};

__global__ __launch_bounds__(256) void mega(MegaArgs a)
{
    __shared__ __align__(16) char smem[32768];
    const int bid = blockIdx.x, t = threadIdx.x;

    // ---------------- phase A ----------------
    #pragma unroll
    for (int i = 0; i < 8; ++i) {
        const int unit = bid + NBLK_ * i;
        if (unit < 1024) {
            size_t idx = ((size_t)unit * 256 + t) * 8;
            float4 va = *(const float4*)&a.x[idx];
            float4 vb = *(const float4*)&a.x[idx + 4];
            float f[8] = {va.x, va.y, va.z, va.w, vb.x, vb.y, vb.z, vb.w};
            ushort8v hh;
            #pragma unroll
            for (int j = 0; j < 8; ++j) hh[j] = f2h(f[j]);
            *(ushort8v*)&a.xh[idx] = hh;
        } else {
            float (*tile)[33] = (float (*)[33])smem;
            const float* W; unsigned short* Whi; int N, k0, n0;
            int u = unit - 1024;
            if (u < 768) { W = a.Wq; Whi = a.wqh; N = NQKV_; n0 = (u % 48) * 32; k0 = (u / 48) * 32; }
            else { u -= 768; W = a.Wo; Whi = a.woh; N = DIM_; n0 = (u % 16) * 32; k0 = (u / 16) * 32; }
            const int c = t & 31, r8 = t >> 5;
            __syncthreads();
            #pragma unroll
            for (int j = 0; j < 4; ++j) {
                int r = r8 + j * 8;
                tile[r][c] = W[(size_t)(k0 + r) * N + n0 + c];
            }
            __syncthreads();
            #pragma unroll
            for (int j = 0; j < 4; ++j) {
                int r = r8 + j * 8;
                Whi[(size_t)(n0 + r) * 512 + k0 + c] = f2h(tile[c][r]);
            }
        }
    }
    if (t < 8) {
        int s = bid * 8 + t;
        atomicAdd(&a.gcnt[a.routes[(size_t)s * K_]], 1);
    }

    gbar(a.bar + 0, NBLK_);

    // ---------------- phase B ----------------
    if (bid == 255) {
        int* cnt  = (int*)smem;
        int* base = cnt + 2048;
        int* cur  = base + 2048;
        int* ps   = cur + 2048;
        for (int i = t; i < 2048; i += 256)
            cnt[i] = __hip_atomic_load(&a.gcnt[i], __ATOMIC_RELAXED, __HIP_MEMORY_SCOPE_AGENT);
        __syncthreads();
        int loc[8], sum = 0;
        #pragma unroll
        for (int i = 0; i < 8; ++i) { loc[i] = sum; sum += cnt[t * 8 + i]; }
        ps[t] = sum;
        __syncthreads();
        for (int off = 1; off < 256; off <<= 1) {
            int v = ps[t];
            if (t >= off) v += ps[t - off];
            __syncthreads(); ps[t] = v; __syncthreads();
        }
        const int excl = ps[t] - sum;
        #pragma unroll
        for (int i = 0; i < 8; ++i) { base[t * 8 + i] = excl + loc[i]; cur[t * 8 + i] = 0; }
        __syncthreads();
        #pragma unroll
        for (int i = 0; i < 8; ++i) {
            int s = i * 256 + t;
            int lead = a.routes[(size_t)s * K_];
            a.members[base[lead] + atomicAdd(&cur[lead], 1)] = s;
        }
        int cloc[8], csum = 0;
        #pragma unroll
        for (int i = 0; i < 8; ++i) { cloc[i] = csum; csum += (cnt[t * 8 + i] + 15) >> 4; }
        __syncthreads();
        ps[t] = csum;
        __syncthreads();
        for (int off = 1; off < 256; off <<= 1) {
            int v = ps[t];
            if (t >= off) v += ps[t - off];
            __syncthreads(); ps[t] = v; __syncthreads();
        }
        const int cexcl = ps[t] - csum;
        #pragma unroll
        for (int i = 0; i < 8; ++i) {
            const int c = t * 8 + i, n = cnt[c];
            int w0 = cexcl + cloc[i];
            for (int k2 = 0; k2 * 16 < n; ++k2) {
                int rem = n - k2 * 16;
                a.recs[w0 + k2] = make_int4(c, base[c] + k2 * 16, rem < 16 ? rem : 16, 0);
            }
        }
        if (t == 255)
            __hip_atomic_store(a.nchp, ps[255], __ATOMIC_RELAXED, __HIP_MEMORY_SCOPE_AGENT);
    } else {
        for (int tid = bid; tid < 512; tid += 255) {
            gemm_tile<128, 96, 64, 48>(smem, a.xh, a.wqh, a.bqkv, nullptr,
                                       a.Qh, a.Kh, a.Vh, NQKV_, DIM_, 1,
                                       (tid >> 4) * 128, (tid & 15) * 96);
            __syncthreads();
        }
    }

    gbar(a.bar + 1, NBLK_);

    // ---------------- phase C ----------------
    {
        const int wv = t >> 6;
        unsigned short* Vlds = (unsigned short*)smem + wv * 4096;
        int nch = __hip_atomic_load(a.nchp, __ATOMIC_RELAXED, __HIP_MEMORY_SCOPE_AGENT);
        nch = nch < 0 ? 0 : (nch > 2048 ? 2048 : nch);   // clamp: poison can't fault
        const int total = nch * 16;
        for (int idx = bid * 4 + wv; idx < total; idx += NBLK_ * 4) {
            attn_one(idx & 15, idx >> 4, Vlds,
                     a.Qh, a.Kh, a.Vh, a.routes, a.members, a.recs, a.ah);
        }
    }

    gbar(a.bar + 2, NBLK_);

    // ---------------- phase D ----------------
    for (int tid = bid; tid < 512; tid += NBLK_) {
        gemm_tile<64, 64, 32, 32>(smem, a.ah, a.woh, a.bout, a.out,
                                  nullptr, nullptr, nullptr, DIM_, DIM_, 0,
                                  (tid >> 3) * 64, (tid & 7) * 64);
        __syncthreads();
    }
}

// ---------------------------------------------------------------------------
// ws layout (bytes):
//   0    Q fp16 4MB | 8M K fp16 4MB | 16M V fp16 4MB
//   24M  x_h / attn fp16 4MB
//   32M  Wqkv_h 1.5M | +1.5M Wout_h 0.5M
//   34M  members[2048] | +8K recs int4[2048] | +40K nchp | +48K gcnt[2048] | +56K bar[16]
// ---------------------------------------------------------------------------
extern "C" void kernel_launch(void* const* d_in, const int* in_sizes, int n_in,
                              void* d_out, int out_size, void* d_ws, size_t ws_size,
                              hipStream_t stream)
{
    const float* x      = (const float*)d_in[0];
    const float* Wqkv   = (const float*)d_in[1];
    const float* bqkv   = (const float*)d_in[2];
    const float* Wout   = (const float*)d_in[3];
    const float* bout   = (const float*)d_in[4];
    const int*   routes = (const int*)d_in[5];
    float* out = (float*)d_out;

    char* w = (char*)d_ws;
    unsigned short* Qh = (unsigned short*)(w);
    unsigned short* Kh = (unsigned short*)(w + (8u << 20));
    unsigned short* Vh = (unsigned short*)(w + (16u << 20));
    unsigned short* xh = (unsigned short*)(w + (24u << 20));
    unsigned short* ah = xh;   // aliased: free after qkv gemm
    unsigned short* wqh = (unsigned short*)(w + (32u << 20));
    unsigned short* woh = (unsigned short*)(w + (32u << 20) + 1572864u);
    int*  members = (int*)(w + (34u << 20));
    int4* recs    = (int4*)(w + (34u << 20) + 8192u);
    int*  nchp    = (int*)(w + (34u << 20) + 8192u + 32768u);
    int*  gcnt    = (int*)(w + (34u << 20) + 49152u);
    int*  bar     = (int*)(w + (34u << 20) + 49152u + 8192u);

    MegaArgs A;
    A.x = x; A.xh = xh; A.Wq = Wqkv; A.wqh = wqh; A.Wo = Wout; A.woh = woh;
    A.bqkv = bqkv; A.bout = bout; A.routes = routes;
    A.members = members; A.recs = recs; A.nchp = nchp; A.gcnt = gcnt; A.bar = bar;
    A.Qh = Qh; A.Kh = Kh; A.Vh = Vh; A.ah = ah; A.out = out;

    zero_ws<<<dim3(8), dim3(256), 0, stream>>>(gcnt, bar, nchp);
    mega<<<dim3(NBLK_), dim3(256), 0, stream>>>(A);
}

// Round 9
// 117.576 us; speedup vs baseline: 2.4714x; 2.4714x over previous
//
#include <hip/hip_runtime.h>
#include <math.h>

// CantorAttention: B=2, S=2048, DIM=512, H=8, HD=64, K=64
#define B_    2
#define S_    2048
#define DIM_  512
#define H_    8
#define HD_   64
#define K_    64
#define M_    (B_ * S_)          // 4096
#define NQKV_ (3 * DIM_)         // 1536

typedef __attribute__((ext_vector_type(8))) _Float16       half8;     // mfma A/B frag (8 f16)
typedef __attribute__((ext_vector_type(8))) unsigned short ushort8v;  // 16B move
typedef __attribute__((ext_vector_type(4))) float          float4v;   // mfma C/D frag

union H8 { half8 h; ushort8v u; unsigned int w[4]; };

// ---- fp16 helpers ----------------------------------------------------------
__device__ __forceinline__ unsigned short f2h(float f) {
    _Float16 h = (_Float16)f;
    unsigned short u; __builtin_memcpy(&u, &h, 2); return u;
}
__device__ __forceinline__ unsigned int pkrtz(float a, float b) {
    auto r = __builtin_amdgcn_cvt_pkrtz(a, b);   // __fp16x2: D.lo=a, D.hi=b
    unsigned int u; __builtin_memcpy(&u, &r, 4); return u;
}

// async 16B global -> LDS (lane l lands at ldsbase + l*16; per-lane global src)
__device__ __forceinline__ void load_lds16(const unsigned short* g, unsigned short* l) {
    __builtin_amdgcn_global_load_lds(
        (const __attribute__((address_space(1))) void*)g,
        (__attribute__((address_space(3))) void*)l, 16, 0, 0);
}

// ---------------------------------------------------------------------------
// prep_all (shrunk): W transposes + route grouping only. The x fp32->fp16
// conversion moved into the qkv GEMM's A-staging (round-9 change) -- saves a
// 1024-block pass and 16 MB of xh write+read traffic.
//   [0,768):    transpose Wqkv -> fp16 [N][Kd] (48 x 16 tiles of 32x32)
//   [768,1024): transpose Wout -> fp16 (16 x 16 tiles)
//   [1024]:     route class grouping (16-member chunks; routes[s][0] is a
//               perfect class key -- validated rounds 1/3/5)
// ---------------------------------------------------------------------------
__global__ __launch_bounds__(256) void prep_all(
    const float* __restrict__ Wq, unsigned short* __restrict__ Wqh,
    const float* __restrict__ Wo, unsigned short* __restrict__ Woh,
    const int* __restrict__ routes, int* __restrict__ members,
    int4* __restrict__ recs, int* __restrict__ nchp)
{
    __shared__ int smem[2048 * 3 + 256];
    const int bid = blockIdx.x, t = threadIdx.x;

    if (bid == 1024) {
        int* cnt  = smem;            // [2048]
        int* base = smem + 2048;     // [2048]
        int* cur  = smem + 4096;     // [2048]
        int* ps   = smem + 6144;     // [256]
        for (int i = t; i < 2048; i += 256) cnt[i] = 0;
        __syncthreads();
        int lead[8];
        #pragma unroll
        for (int i = 0; i < 8; ++i) {
            lead[i] = routes[(size_t)(i * 256 + t) * K_];
            atomicAdd(&cnt[lead[i]], 1);
        }
        __syncthreads();
        int loc[8], sum = 0;
        #pragma unroll
        for (int i = 0; i < 8; ++i) { loc[i] = sum; sum += cnt[t * 8 + i]; }
        ps[t] = sum;
        __syncthreads();
        for (int off = 1; off < 256; off <<= 1) {
            int v = ps[t];
            if (t >= off) v += ps[t - off];
            __syncthreads(); ps[t] = v; __syncthreads();
        }
        const int excl = ps[t] - sum;
        #pragma unroll
        for (int i = 0; i < 8; ++i) { base[t * 8 + i] = excl + loc[i]; cur[t * 8 + i] = 0; }
        __syncthreads();
        #pragma unroll
        for (int i = 0; i < 8; ++i) {
            int s = i * 256 + t;
            members[base[lead[i]] + atomicAdd(&cur[lead[i]], 1)] = s;
        }
        // chunk records: ceil(cnt/16) per class (16-member chunks)
        int cloc[8], csum = 0;
        #pragma unroll
        for (int i = 0; i < 8; ++i) { cloc[i] = csum; csum += (cnt[t * 8 + i] + 15) >> 4; }
        __syncthreads();
        ps[t] = csum;
        __syncthreads();
        for (int off = 1; off < 256; off <<= 1) {
            int v = ps[t];
            if (t >= off) v += ps[t - off];
            __syncthreads(); ps[t] = v; __syncthreads();
        }
        const int cexcl = ps[t] - csum;
        #pragma unroll
        for (int i = 0; i < 8; ++i) {
            const int c = t * 8 + i, n = cnt[c];
            int w0 = cexcl + cloc[i];
            for (int k2 = 0; k2 * 16 < n; ++k2) {
                int rem = n - k2 * 16;
                recs[w0 + k2] = make_int4(c, base[c] + k2 * 16, rem < 16 ? rem : 16, 0);
            }
        }
        if (t == 255) nchp[0] = ps[255];
        return;
    }

    float (*tile)[33] = (float (*)[33])smem;
    const float* W;
    unsigned short* Whi;
    int N, k0, n0;
    if (bid < 768) {
        W = Wq; Whi = Wqh; N = NQKV_;
        n0 = (bid % 48) * 32; k0 = (bid / 48) * 32;
    } else {
        int idx = bid - 768;                   // 256 blocks: 16 x 16
        W = Wo; Whi = Woh; N = DIM_;
        n0 = (idx % 16) * 32; k0 = (idx / 16) * 32;
    }
    const int c = t & 31, r8 = t >> 5;
    #pragma unroll
    for (int i = 0; i < 4; ++i) {
        int r = r8 + i * 8;
        tile[r][c] = W[(size_t)(k0 + r) * N + n0 + c];
    }
    __syncthreads();
    #pragma unroll
    for (int i = 0; i < 4; ++i) {
        int r = r8 + i * 8;
        Whi[(size_t)(n0 + r) * 512 + k0 + c] = f2h(tile[c][r]);   // Kd = 512
    }
}

// ---------------------------------------------------------------------------
// fp16 MFMA GEMM (round-5 verified structure).
//   AF32=true : A source is fp32 (x); staged via regs with inline fp32->fp16
//               conversion + ds_write_b128 to the IDENTICAL LDS layout
//               (T14: loads issued before the MFMA block, write after).
//   AF32=false: A source fp16, gload_lds staging (verified path).
//   mode 0: row-major fp32 C.  mode 1: qkv scatter -> Q/K/V fp16 [B,H,S,HD],
//           SCALE=0.125 folded into Q.
// ---------------------------------------------------------------------------
template<int BM, int BN, int WM, int WN, bool AF32>
__global__ __launch_bounds__(256) void gemm_mfma(
    const void* __restrict__ Asrc, const unsigned short* __restrict__ Wh,
    const float* __restrict__ bias, float* __restrict__ C,
    unsigned short* __restrict__ Qho, unsigned short* __restrict__ Kho,
    unsigned short* __restrict__ Vho,
    int N, int Kd, int mode)
{
    constexpr int TM = WM / 16, TN = WN / 16;
    constexpr int WAVES_N = BN / WN;
    static_assert(!AF32 || BM == 128, "AF32 prefetch sized for BM=128/4 waves");
    __shared__ unsigned short Ah[2][BM][32];
    __shared__ unsigned short Bh[2][BN][32];

    const unsigned short* A16 = (const unsigned short*)Asrc;
    const float*          A32 = (const float*)Asrc;

    const int t = threadIdx.x, lane = t & 63, wave = t >> 6;
    const int wm = (wave / WAVES_N) * WM, wn = (wave % WAVES_N) * WN;
    const int m0 = blockIdx.y * BM, n0 = blockIdx.x * BN;
    const int l15 = lane & 15, l4 = lane >> 4;
    const int srow = lane >> 2;          // 0..15
    const int scol = (lane & 3) * 8;     // 0,8,16,24

    float4v acc[TM][TN];
    #pragma unroll
    for (int i = 0; i < TM; ++i)
        #pragma unroll
        for (int j = 0; j < TN; ++j)
            #pragma unroll
            for (int r = 0; r < 4; ++r) acc[i][j][r] = 0.f;

    const int NK = Kd / 32;

    // ---- stage 0 ----
    #pragma unroll
    for (int c = wave; c < BM / 16; c += 4) {
        if constexpr (AF32) {
            const float* xr = &A32[(size_t)(m0 + c * 16 + srow) * Kd + scol];
            float4 f0 = *(const float4*)xr;
            float4 f1 = *(const float4*)(xr + 4);
            ushort8v hh;
            hh[0] = f2h(f0.x); hh[1] = f2h(f0.y); hh[2] = f2h(f0.z); hh[3] = f2h(f0.w);
            hh[4] = f2h(f1.x); hh[5] = f2h(f1.y); hh[6] = f2h(f1.z); hh[7] = f2h(f1.w);
            *(ushort8v*)&Ah[0][c * 16 + srow][scol] = hh;
        } else {
            size_t g = (size_t)(m0 + c * 16 + srow) * Kd + scol;
            load_lds16(&A16[g], &Ah[0][c * 16][0]);
        }
    }
    #pragma unroll
    for (int c = wave; c < BN / 16; c += 4) {
        size_t g = (size_t)(n0 + c * 16 + srow) * Kd + scol;
        load_lds16(&Wh[g], &Bh[0][c * 16][0]);
    }
    __syncthreads();

    for (int ks = 0; ks < NK; ++ks) {
        const int cur = ks & 1, nxt = cur ^ 1;

        float4 pf[2][2];   // AF32 prefetch regs (2 c-groups x 2 float4)
        if (ks + 1 < NK) {
            const int k1 = (ks + 1) * 32;
            if constexpr (AF32) {
                #pragma unroll
                for (int i = 0; i < 2; ++i) {
                    const int c = wave + i * 4;
                    const float* xr = &A32[(size_t)(m0 + c * 16 + srow) * Kd + k1 + scol];
                    pf[i][0] = *(const float4*)xr;
                    pf[i][1] = *(const float4*)(xr + 4);
                }
            } else {
                #pragma unroll
                for (int c = wave; c < BM / 16; c += 4) {
                    size_t g = (size_t)(m0 + c * 16 + srow) * Kd + k1 + scol;
                    load_lds16(&A16[g], &Ah[nxt][c * 16][0]);
                }
            }
            #pragma unroll
            for (int c = wave; c < BN / 16; c += 4) {
                size_t g = (size_t)(n0 + c * 16 + srow) * Kd + k1 + scol;
                load_lds16(&Wh[g], &Bh[nxt][c * 16][0]);
            }
        }

        half8 fa[TM], fb[TN];
        #pragma unroll
        for (int im = 0; im < TM; ++im)
            fa[im] = *(const half8*)&Ah[cur][wm + im * 16 + l15][l4 * 8];
        #pragma unroll
        for (int in = 0; in < TN; ++in)
            fb[in] = *(const half8*)&Bh[cur][wn + in * 16 + l15][l4 * 8];
        #pragma unroll
        for (int im = 0; im < TM; ++im)
            #pragma unroll
            for (int in = 0; in < TN; ++in)
                acc[im][in] = __builtin_amdgcn_mfma_f32_16x16x32_f16(fa[im], fb[in], acc[im][in], 0, 0, 0);

        if constexpr (AF32) {
            if (ks + 1 < NK) {
                // write-late: fp32 loads have had the MFMA block to land
                #pragma unroll
                for (int i = 0; i < 2; ++i) {
                    const int c = wave + i * 4;
                    ushort8v hh;
                    hh[0] = f2h(pf[i][0].x); hh[1] = f2h(pf[i][0].y);
                    hh[2] = f2h(pf[i][0].z); hh[3] = f2h(pf[i][0].w);
                    hh[4] = f2h(pf[i][1].x); hh[5] = f2h(pf[i][1].y);
                    hh[6] = f2h(pf[i][1].z); hh[7] = f2h(pf[i][1].w);
                    *(ushort8v*)&Ah[nxt][c * 16 + srow][scol] = hh;
                }
            }
        }

        __syncthreads();
    }

    // epilogue: D row = (lane>>4)*4 + reg, col = lane&15  [m89-verified layout]
    if (mode == 0) {
        #pragma unroll
        for (int in = 0; in < TN; ++in) {
            int n = n0 + wn + in * 16 + l15;
            float bv = bias[n];
            #pragma unroll
            for (int im = 0; im < TM; ++im) {
                int mb = m0 + wm + im * 16 + l4 * 4;
                #pragma unroll
                for (int r = 0; r < 4; ++r)
                    C[(size_t)(mb + r) * N + n] = acc[im][in][r] + bv;
            }
        }
    } else {
        #pragma unroll
        for (int in = 0; in < TN; ++in) {
            int n = n0 + wn + in * 16 + l15;
            int which = n >> 9, h = (n >> 6) & 7, d = n & 63;
            unsigned short* dst = (which == 0) ? Qho : (which == 1 ? Kho : Vho);
            float bv = bias[n];
            float scl = (which == 0) ? 0.125f : 1.0f;   // fold attention SCALE into Q
            #pragma unroll
            for (int im = 0; im < TM; ++im) {
                int mb = m0 + wm + im * 16 + l4 * 4;
                #pragma unroll
                for (int r = 0; r < 4; ++r) {
                    int m = mb + r, b = m >> 11, s = m & 2047;
                    dst[(((size_t)b * H_ + h) * S_ + s) * HD_ + d] =
                        f2h((acc[im][in][r] + bv) * scl);
                }
            }
        }
    }
}

// ---------------------------------------------------------------------------
// MFMA class-grouped attention (round-5 verified, byte-identical).
// One wave = one chunk of <=16 member rows of one route class.
// ---------------------------------------------------------------------------
__global__ __launch_bounds__(256, 4) void attn_kernel(
    const unsigned short* __restrict__ Qh, const unsigned short* __restrict__ Kh,
    const unsigned short* __restrict__ Vh, const int* __restrict__ routes,
    const int* __restrict__ members, const int4* __restrict__ recs,
    const int* __restrict__ nchp, unsigned short* __restrict__ Oh)
{
    __shared__ unsigned short VldsAll[4][4096];   // 8KB per wave, [key][d] f16
    const int wv = threadIdx.x >> 6, lane = threadIdx.x & 63;
    unsigned short* Vlds = VldsAll[wv];
    const int g = lane >> 4, m16 = lane & 15;

    const int unit = blockIdx.x * 4 + wv;         // [0, 8192)
    const int bh = unit & 15, cidx = unit >> 4;   // cidx in [0, 512)
    const int b = bh >> 3, h = bh & 7;

    const unsigned short* qbase = Qh + (size_t)bh * S_ * HD_;
    const unsigned short* kbase = Kh + (size_t)bh * S_ * HD_;
    const unsigned short* vbase = Vh + (size_t)bh * S_ * HD_;
    const int nch = nchp[0];

    for (int chunk = cidx; chunk < nch; chunk += 512) {
        const int4 rec = recs[chunk];
        const int leader = rec.x, mstart = rec.y, mcnt = rec.z;

        const int rl = routes[(size_t)leader * K_ + lane];   // route entry per lane
        const int mm = members[mstart + (m16 < mcnt ? m16 : mcnt - 1)];

        // ---- V -> wave-private LDS (linear dest; source chunk pre-swizzled:
        // dest [key][c] holds V[key][c ^ (key>>3)]) ----
        #pragma unroll
        for (int i = 0; i < 8; ++i) {
            int rv = __shfl(rl, i * 8 + (lane >> 3));
            int sc = (lane & 7) ^ i;
            load_lds16(&vbase[(size_t)rv * HD_ + sc * 8], Vlds + i * 512);
        }

        // ---- K A-frags: row=key-in-tile (m16), k=d chunk g*8 + 32s ----
        H8 ka[4][2];
        #pragma unroll
        for (int tt = 0; tt < 4; ++tt) {
            int rt = __shfl(rl, tt * 16 + m16);
            const unsigned short* kr = &kbase[(size_t)rt * HD_];
            ka[tt][0].u = *(const ushort8v*)(kr + g * 8);
            ka[tt][1].u = *(const ushort8v*)(kr + 32 + g * 8);
        }
        // ---- Q B-frags: col=m16 (own member row; Q pre-scaled by 0.125) ----
        const unsigned short* qr = &qbase[(size_t)mm * HD_];
        H8 qb0, qb1;
        qb0.u = *(const ushort8v*)(qr + g * 8);
        qb1.u = *(const ushort8v*)(qr + 32 + g * 8);

        // ---- scores: D[key=16t+4g+r][m=m16] ----
        float4v acc[4];
        #pragma unroll
        for (int tt = 0; tt < 4; ++tt) {
            #pragma unroll
            for (int r = 0; r < 4; ++r) acc[tt][r] = 0.f;
        }
        #pragma unroll
        for (int tt = 0; tt < 4; ++tt) {
            acc[tt] = __builtin_amdgcn_mfma_f32_16x16x32_f16(ka[tt][0].h, qb0.h, acc[tt], 0, 0, 0);
            acc[tt] = __builtin_amdgcn_mfma_f32_16x16x32_f16(ka[tt][1].h, qb1.h, acc[tt], 0, 0, 0);
        }

        // ---- softmax over 64 keys for this lane's m ----
        float mx = acc[0][0];
        #pragma unroll
        for (int tt = 0; tt < 4; ++tt)
            #pragma unroll
            for (int r = 0; r < 4; ++r) mx = fmaxf(mx, acc[tt][r]);
        mx = fmaxf(mx, __shfl_xor(mx, 16));
        mx = fmaxf(mx, __shfl_xor(mx, 32));
        float ew[4][4], su = 0.f;
        #pragma unroll
        for (int tt = 0; tt < 4; ++tt)
            #pragma unroll
            for (int r = 0; r < 4; ++r) { ew[tt][r] = __expf(acc[tt][r] - mx); su += ew[tt][r]; }
        su += __shfl_xor(su, 16);
        su += __shfl_xor(su, 32);
        const float rinv = __builtin_amdgcn_rcpf(su);

        unsigned int whu[4][2];
        #pragma unroll
        for (int tt = 0; tt < 4; ++tt) {
            whu[tt][0] = pkrtz(ew[tt][0] * rinv, ew[tt][1] * rinv);
            whu[tt][1] = pkrtz(ew[tt][2] * rinv, ew[tt][3] * rinv);
        }

        // ---- P redistribution: C-layout (key=16t+4g+r @ col m) ->
        // A-frag (row m=m16, k=key 32s+8g+j) ----
        const int A0 = (((g & 1) << 5) | m16) * 4;
        const int A1 = A0 + 64;
        const bool ghi = (g >> 1) != 0;
        H8 pa[2];
        #pragma unroll
        for (int s = 0; s < 2; ++s) {
            unsigned int l0a = (unsigned int)__builtin_amdgcn_ds_bpermute(A0, (int)whu[2 * s][0]);
            unsigned int l0b = (unsigned int)__builtin_amdgcn_ds_bpermute(A0, (int)whu[2 * s + 1][0]);
            unsigned int h0a = (unsigned int)__builtin_amdgcn_ds_bpermute(A0, (int)whu[2 * s][1]);
            unsigned int h0b = (unsigned int)__builtin_amdgcn_ds_bpermute(A0, (int)whu[2 * s + 1][1]);
            unsigned int l1a = (unsigned int)__builtin_amdgcn_ds_bpermute(A1, (int)whu[2 * s][0]);
            unsigned int l1b = (unsigned int)__builtin_amdgcn_ds_bpermute(A1, (int)whu[2 * s + 1][0]);
            unsigned int h1a = (unsigned int)__builtin_amdgcn_ds_bpermute(A1, (int)whu[2 * s][1]);
            unsigned int h1b = (unsigned int)__builtin_amdgcn_ds_bpermute(A1, (int)whu[2 * s + 1][1]);
            pa[s].w[0] = ghi ? l0b : l0a;
            pa[s].w[1] = ghi ? h0b : h0a;
            pa[s].w[2] = ghi ? l1b : l1a;
            pa[s].w[3] = ghi ? h1b : h1a;
        }

        // member rows for the store (D row m = g*4+r)
        int mr[4];
        #pragma unroll
        for (int r = 0; r < 4; ++r)
            mr[r] = __builtin_amdgcn_ds_bpermute((g * 4 + r) * 4, mm);

        // V DMA must have landed before the column reads
        asm volatile("s_waitcnt vmcnt(0)" ::: "memory");
        __builtin_amdgcn_sched_barrier(0);

        // ---- PV per 16-wide d-block: B col = d (m16), k = key ----
        #pragma unroll
        for (int dblk = 0; dblk < 4; ++dblk) {
            H8 vb[2];
            #pragma unroll
            for (int s = 0; s < 2; ++s) {
                const char* vp = (const char*)Vlds + (s * 32 + g * 8) * 128 +
                    (((dblk * 16 + m16) * 2) ^ ((((s * 4 + g) & 7)) << 4));
                #pragma unroll
                for (int j = 0; j < 8; ++j)
                    vb[s].u[j] = *(const unsigned short*)(vp + j * 128);
            }
            float4v o;
            o[0] = 0.f; o[1] = 0.f; o[2] = 0.f; o[3] = 0.f;
            o = __builtin_amdgcn_mfma_f32_16x16x32_f16(pa[0].h, vb[0].h, o, 0, 0, 0);
            o = __builtin_amdgcn_mfma_f32_16x16x32_f16(pa[1].h, vb[1].h, o, 0, 0, 0);
            #pragma unroll
            for (int r = 0; r < 4; ++r) {
                if (g * 4 + r < mcnt) {
                    size_t oi = ((size_t)b * S_ + mr[r]) * DIM_ + h * HD_ + dblk * 16 + m16;
                    Oh[oi] = f2h(o[r]);
                }
            }
        }
    }
}

// ---------------------------------------------------------------------------
// ws layout (bytes):
//   0    Q fp16 4MB | 8M K fp16 4MB | 16M V fp16 4MB
//   24M  attn out fp16 4MB (xh no longer exists -- conversion fused into qkv)
//   32M  Wqkv_h fp16 1.5M | +1.5M Wout_h fp16 0.5M
//   34M  members int[2048] | +8K recs int4[2048] | +40K nChunks
// ---------------------------------------------------------------------------
extern "C" void kernel_launch(void* const* d_in, const int* in_sizes, int n_in,
                              void* d_out, int out_size, void* d_ws, size_t ws_size,
                              hipStream_t stream)
{
    const float* x      = (const float*)d_in[0];
    const float* Wqkv   = (const float*)d_in[1];
    const float* bqkv   = (const float*)d_in[2];
    const float* Wout   = (const float*)d_in[3];
    const float* bout   = (const float*)d_in[4];
    const int*   routes = (const int*)d_in[5];
    float* out = (float*)d_out;

    char* w = (char*)d_ws;
    unsigned short* Qh = (unsigned short*)(w);
    unsigned short* Kh = (unsigned short*)(w + (8u << 20));
    unsigned short* Vh = (unsigned short*)(w + (16u << 20));
    unsigned short* ah = (unsigned short*)(w + (24u << 20));
    unsigned short* wqh = (unsigned short*)(w + (32u << 20));
    unsigned short* woh = (unsigned short*)(w + (32u << 20) + 1572864u);
    int*  members = (int*)(w + (34u << 20));
    int4* recs    = (int4*)(w + (34u << 20) + 8192u);
    int*  nchp    = (int*)(w + (34u << 20) + 8192u + 32768u);

    dim3 blk(256);

    // prep: W transposes (1024 blocks) + grouping (1 block)
    prep_all<<<dim3(1025), blk, 0, stream>>>(Wqkv, wqh, Wout, woh,
                                             routes, members, recs, nchp);

    // qkv: M=4096, N=1536, K=512; A = x fp32 with fused conversion
    gemm_mfma<128, 96, 64, 48, true><<<dim3(NQKV_ / 96, M_ / 128), blk, 0, stream>>>(
        x, wqh, bqkv, nullptr, Qh, Kh, Vh, NQKV_, DIM_, 1);

    attn_kernel<<<dim3(2048), blk, 0, stream>>>(Qh, Kh, Vh, routes,
                                                members, recs, nchp, ah);

    // out-proj: M=4096, N=512, K=512; A = ah fp16 (gload_lds path)
    gemm_mfma<64, 64, 32, 32, false><<<dim3(DIM_ / 64, M_ / 64), blk, 0, stream>>>(
        ah, woh, bout, out, nullptr, nullptr, nullptr, DIM_, DIM_, 0);
}

// Round 10
// 116.568 us; speedup vs baseline: 2.4928x; 1.0086x over previous
//
#include <hip/hip_runtime.h>
#include <math.h>

// CantorAttention: B=2, S=2048, DIM=512, H=8, HD=64, K=64
#define B_    2
#define S_    2048
#define DIM_  512
#define H_    8
#define HD_   64
#define K_    64
#define M_    (B_ * S_)          // 4096
#define NQKV_ (3 * DIM_)         // 1536

typedef __attribute__((ext_vector_type(8))) _Float16       half8;     // mfma A/B frag (8 f16)
typedef __attribute__((ext_vector_type(8))) unsigned short ushort8v;  // 16B move
typedef __attribute__((ext_vector_type(4))) float          float4v;   // mfma C/D frag

union H8 { half8 h; ushort8v u; unsigned int w[4]; };

// ---- fp16 helpers ----------------------------------------------------------
__device__ __forceinline__ unsigned short f2h(float f) {
    _Float16 h = (_Float16)f;
    unsigned short u; __builtin_memcpy(&u, &h, 2); return u;
}
__device__ __forceinline__ unsigned int pkrtz(float a, float b) {
    auto r = __builtin_amdgcn_cvt_pkrtz(a, b);   // __fp16x2: D.lo=a, D.hi=b
    unsigned int u; __builtin_memcpy(&u, &r, 4); return u;
}

// async 16B global -> LDS (lane l lands at ldsbase + l*16; per-lane global src)
__device__ __forceinline__ void load_lds16(const unsigned short* g, unsigned short* l) {
    __builtin_amdgcn_global_load_lds(
        (const __attribute__((address_space(1))) void*)g,
        (__attribute__((address_space(3))) void*)l, 16, 0, 0);
}

// ---------------------------------------------------------------------------
// prep_all: W transposes + route grouping.
//   [0,768):    transpose Wqkv -> fp16 [N][Kd] (48 x 16 tiles of 32x32)
//   [768,1024): transpose Wout -> fp16 (16 x 16 tiles)
//   [1024]:     route class grouping. Round-10 change: the two 256-wide
//               Hillis-Steele scans (~64 __syncthreads in one block, ~5us of
//               barrier latency) replaced by wave-level __shfl_up scans +
//               4-wave combine (3 barriers).
// ---------------------------------------------------------------------------
__global__ __launch_bounds__(256) void prep_all(
    const float* __restrict__ Wq, unsigned short* __restrict__ Wqh,
    const float* __restrict__ Wo, unsigned short* __restrict__ Woh,
    const int* __restrict__ routes, int* __restrict__ members,
    int4* __restrict__ recs, int* __restrict__ nchp)
{
    __shared__ int smem[2048 * 3 + 256];
    const int bid = blockIdx.x, t = threadIdx.x;

    if (bid == 1024) {
        int* cnt  = smem;            // [2048] per-leader member count
        int* base = smem + 2048;     // [2048] member segment start
        int* cur  = smem + 4096;     // [2048] scatter cursor
        int* wtot = smem + 6144;     // [4]    per-wave scan totals
        const int lane = t & 63, wv = t >> 6;

        for (int i = t; i < 2048; i += 256) cnt[i] = 0;
        __syncthreads();
        int lead[8];
        #pragma unroll
        for (int i = 0; i < 8; ++i) {
            lead[i] = routes[(size_t)(i * 256 + t) * K_];
            atomicAdd(&cnt[lead[i]], 1);
        }
        __syncthreads();

        // scan 1 (member bases): thread t owns classes [8t, 8t+8)
        int loc[8], sum = 0;
        #pragma unroll
        for (int i = 0; i < 8; ++i) { loc[i] = sum; sum += cnt[t * 8 + i]; }
        int v = sum;                              // wave-inclusive scan
        #pragma unroll
        for (int off = 1; off < 64; off <<= 1) {
            int u = __shfl_up(v, off);
            if (lane >= off) v += u;
        }
        if (lane == 63) wtot[wv] = v;
        __syncthreads();
        int add = 0;
        #pragma unroll
        for (int w2 = 0; w2 < 4; ++w2) add += (w2 < wv) ? wtot[w2] : 0;
        const int excl = v + add - sum;           // exclusive prefix for thread t
        #pragma unroll
        for (int i = 0; i < 8; ++i) { base[t * 8 + i] = excl + loc[i]; cur[t * 8 + i] = 0; }
        __syncthreads();
        #pragma unroll
        for (int i = 0; i < 8; ++i) {
            int s = i * 256 + t;
            members[base[lead[i]] + atomicAdd(&cur[lead[i]], 1)] = s;
        }

        // scan 2 (chunk records): ceil(cnt/16) per class (16-member chunks)
        int cloc[8], csum = 0;
        #pragma unroll
        for (int i = 0; i < 8; ++i) { cloc[i] = csum; csum += (cnt[t * 8 + i] + 15) >> 4; }
        int v2 = csum;
        #pragma unroll
        for (int off = 1; off < 64; off <<= 1) {
            int u = __shfl_up(v2, off);
            if (lane >= off) v2 += u;
        }
        if (lane == 63) wtot[wv] = v2;
        __syncthreads();
        int add2 = 0;
        #pragma unroll
        for (int w2 = 0; w2 < 4; ++w2) add2 += (w2 < wv) ? wtot[w2] : 0;
        const int cexcl = v2 + add2 - csum;
        #pragma unroll
        for (int i = 0; i < 8; ++i) {
            const int c = t * 8 + i, n = cnt[c];
            int w0 = cexcl + cloc[i];
            for (int k2 = 0; k2 * 16 < n; ++k2) {
                int rem = n - k2 * 16;
                recs[w0 + k2] = make_int4(c, base[c] + k2 * 16, rem < 16 ? rem : 16, 0);
            }
        }
        if (t == 255) nchp[0] = v2 + add2;        // inclusive total = chunk count
        return;
    }

    float (*tile)[33] = (float (*)[33])smem;
    const float* W;
    unsigned short* Whi;
    int N, k0, n0;
    if (bid < 768) {
        W = Wq; Whi = Wqh; N = NQKV_;
        n0 = (bid % 48) * 32; k0 = (bid / 48) * 32;
    } else {
        int idx = bid - 768;                   // 256 blocks: 16 x 16
        W = Wo; Whi = Woh; N = DIM_;
        n0 = (idx % 16) * 32; k0 = (idx / 16) * 32;
    }
    const int c = t & 31, r8 = t >> 5;
    #pragma unroll
    for (int i = 0; i < 4; ++i) {
        int r = r8 + i * 8;
        tile[r][c] = W[(size_t)(k0 + r) * N + n0 + c];
    }
    __syncthreads();
    #pragma unroll
    for (int i = 0; i < 4; ++i) {
        int r = r8 + i * 8;
        Whi[(size_t)(n0 + r) * 512 + k0 + c] = f2h(tile[c][r]);   // Kd = 512
    }
}

// ---------------------------------------------------------------------------
// fp16 MFMA GEMM (round-5 verified structure; AGR generalizes the AF32
// prefetch to any BM).
//   AF32=true : A source fp32 (x); reg-staged with inline fp32->fp16 convert
//               + ds_write to the IDENTICAL LDS layout (issue-early/write-late).
//   AF32=false: A source fp16, gload_lds staging.
//   mode 0: row-major fp32 C.  mode 1: qkv scatter -> Q/K/V fp16 [B,H,S,HD],
//           SCALE=0.125 folded into Q.
// Round-10: qkv instantiated at BM=64 (grid 1024 = 4 blocks/CU) -- this GEMM
// is staging-latency-bound, not compute-bound; doubling co-resident blocks
// doubles cross-block overlap of the per-barrier vmcnt drain (m114 mechanism).
// ---------------------------------------------------------------------------
template<int BM, int BN, int WM, int WN, bool AF32>
__global__ __launch_bounds__(256) void gemm_mfma(
    const void* __restrict__ Asrc, const unsigned short* __restrict__ Wh,
    const float* __restrict__ bias, float* __restrict__ C,
    unsigned short* __restrict__ Qho, unsigned short* __restrict__ Kho,
    unsigned short* __restrict__ Vho,
    int N, int Kd, int mode)
{
    constexpr int TM = WM / 16, TN = WN / 16;
    constexpr int WAVES_N = BN / WN;
    constexpr int AGR = BM / 64;                 // A c-groups per wave
    __shared__ unsigned short Ah[2][BM][32];
    __shared__ unsigned short Bh[2][BN][32];

    const unsigned short* A16 = (const unsigned short*)Asrc;
    const float*          A32 = (const float*)Asrc;

    const int t = threadIdx.x, lane = t & 63, wave = t >> 6;
    const int wm = (wave / WAVES_N) * WM, wn = (wave % WAVES_N) * WN;
    const int m0 = blockIdx.y * BM, n0 = blockIdx.x * BN;
    const int l15 = lane & 15, l4 = lane >> 4;
    const int srow = lane >> 2;          // 0..15
    const int scol = (lane & 3) * 8;     // 0,8,16,24

    float4v acc[TM][TN];
    #pragma unroll
    for (int i = 0; i < TM; ++i)
        #pragma unroll
        for (int j = 0; j < TN; ++j)
            #pragma unroll
            for (int r = 0; r < 4; ++r) acc[i][j][r] = 0.f;

    const int NK = Kd / 32;

    // ---- stage 0 ----
    #pragma unroll
    for (int c = wave; c < BM / 16; c += 4) {
        if constexpr (AF32) {
            const float* xr = &A32[(size_t)(m0 + c * 16 + srow) * Kd + scol];
            float4 f0 = *(const float4*)xr;
            float4 f1 = *(const float4*)(xr + 4);
            ushort8v hh;
            hh[0] = f2h(f0.x); hh[1] = f2h(f0.y); hh[2] = f2h(f0.z); hh[3] = f2h(f0.w);
            hh[4] = f2h(f1.x); hh[5] = f2h(f1.y); hh[6] = f2h(f1.z); hh[7] = f2h(f1.w);
            *(ushort8v*)&Ah[0][c * 16 + srow][scol] = hh;
        } else {
            size_t g = (size_t)(m0 + c * 16 + srow) * Kd + scol;
            load_lds16(&A16[g], &Ah[0][c * 16][0]);
        }
    }
    #pragma unroll
    for (int c = wave; c < BN / 16; c += 4) {
        size_t g = (size_t)(n0 + c * 16 + srow) * Kd + scol;
        load_lds16(&Wh[g], &Bh[0][c * 16][0]);
    }
    __syncthreads();

    for (int ks = 0; ks < NK; ++ks) {
        const int cur = ks & 1, nxt = cur ^ 1;

        float4 pf[AGR][2];   // AF32 prefetch regs
        if (ks + 1 < NK) {
            const int k1 = (ks + 1) * 32;
            if constexpr (AF32) {
                #pragma unroll
                for (int i = 0; i < AGR; ++i) {
                    const int c = wave + i * 4;
                    const float* xr = &A32[(size_t)(m0 + c * 16 + srow) * Kd + k1 + scol];
                    pf[i][0] = *(const float4*)xr;
                    pf[i][1] = *(const float4*)(xr + 4);
                }
            } else {
                #pragma unroll
                for (int c = wave; c < BM / 16; c += 4) {
                    size_t g = (size_t)(m0 + c * 16 + srow) * Kd + k1 + scol;
                    load_lds16(&A16[g], &Ah[nxt][c * 16][0]);
                }
            }
            #pragma unroll
            for (int c = wave; c < BN / 16; c += 4) {
                size_t g = (size_t)(n0 + c * 16 + srow) * Kd + k1 + scol;
                load_lds16(&Wh[g], &Bh[nxt][c * 16][0]);
            }
        }

        half8 fa[TM], fb[TN];
        #pragma unroll
        for (int im = 0; im < TM; ++im)
            fa[im] = *(const half8*)&Ah[cur][wm + im * 16 + l15][l4 * 8];
        #pragma unroll
        for (int in = 0; in < TN; ++in)
            fb[in] = *(const half8*)&Bh[cur][wn + in * 16 + l15][l4 * 8];
        #pragma unroll
        for (int im = 0; im < TM; ++im)
            #pragma unroll
            for (int in = 0; in < TN; ++in)
                acc[im][in] = __builtin_amdgcn_mfma_f32_16x16x32_f16(fa[im], fb[in], acc[im][in], 0, 0, 0);

        if constexpr (AF32) {
            if (ks + 1 < NK) {
                // write-late: fp32 loads have had the MFMA block to land
                #pragma unroll
                for (int i = 0; i < AGR; ++i) {
                    const int c = wave + i * 4;
                    ushort8v hh;
                    hh[0] = f2h(pf[i][0].x); hh[1] = f2h(pf[i][0].y);
                    hh[2] = f2h(pf[i][0].z); hh[3] = f2h(pf[i][0].w);
                    hh[4] = f2h(pf[i][1].x); hh[5] = f2h(pf[i][1].y);
                    hh[6] = f2h(pf[i][1].z); hh[7] = f2h(pf[i][1].w);
                    *(ushort8v*)&Ah[nxt][c * 16 + srow][scol] = hh;
                }
            }
        }

        __syncthreads();
    }

    // epilogue: D row = (lane>>4)*4 + reg, col = lane&15  [m89-verified layout]
    if (mode == 0) {
        #pragma unroll
        for (int in = 0; in < TN; ++in) {
            int n = n0 + wn + in * 16 + l15;
            float bv = bias[n];
            #pragma unroll
            for (int im = 0; im < TM; ++im) {
                int mb = m0 + wm + im * 16 + l4 * 4;
                #pragma unroll
                for (int r = 0; r < 4; ++r)
                    C[(size_t)(mb + r) * N + n] = acc[im][in][r] + bv;
            }
        }
    } else {
        #pragma unroll
        for (int in = 0; in < TN; ++in) {
            int n = n0 + wn + in * 16 + l15;
            int which = n >> 9, h = (n >> 6) & 7, d = n & 63;
            unsigned short* dst = (which == 0) ? Qho : (which == 1 ? Kho : Vho);
            float bv = bias[n];
            float scl = (which == 0) ? 0.125f : 1.0f;   // fold attention SCALE into Q
            #pragma unroll
            for (int im = 0; im < TM; ++im) {
                int mb = m0 + wm + im * 16 + l4 * 4;
                #pragma unroll
                for (int r = 0; r < 4; ++r) {
                    int m = mb + r, b = m >> 11, s = m & 2047;
                    dst[(((size_t)b * H_ + h) * S_ + s) * HD_ + d] =
                        f2h((acc[im][in][r] + bv) * scl);
                }
            }
        }
    }
}

// ---------------------------------------------------------------------------
// MFMA class-grouped attention (round-5 verified, byte-identical).
// One wave = one chunk of <=16 member rows of one route class.
// ---------------------------------------------------------------------------
__global__ __launch_bounds__(256, 4) void attn_kernel(
    const unsigned short* __restrict__ Qh, const unsigned short* __restrict__ Kh,
    const unsigned short* __restrict__ Vh, const int* __restrict__ routes,
    const int* __restrict__ members, const int4* __restrict__ recs,
    const int* __restrict__ nchp, unsigned short* __restrict__ Oh)
{
    __shared__ unsigned short VldsAll[4][4096];   // 8KB per wave, [key][d] f16
    const int wv = threadIdx.x >> 6, lane = threadIdx.x & 63;
    unsigned short* Vlds = VldsAll[wv];
    const int g = lane >> 4, m16 = lane & 15;

    const int unit = blockIdx.x * 4 + wv;         // [0, 8192)
    const int bh = unit & 15, cidx = unit >> 4;   // cidx in [0, 512)
    const int b = bh >> 3, h = bh & 7;

    const unsigned short* qbase = Qh + (size_t)bh * S_ * HD_;
    const unsigned short* kbase = Kh + (size_t)bh * S_ * HD_;
    const unsigned short* vbase = Vh + (size_t)bh * S_ * HD_;
    const int nch = nchp[0];

    for (int chunk = cidx; chunk < nch; chunk += 512) {
        const int4 rec = recs[chunk];
        const int leader = rec.x, mstart = rec.y, mcnt = rec.z;

        const int rl = routes[(size_t)leader * K_ + lane];   // route entry per lane
        const int mm = members[mstart + (m16 < mcnt ? m16 : mcnt - 1)];

        // ---- V -> wave-private LDS (linear dest; source chunk pre-swizzled:
        // dest [key][c] holds V[key][c ^ (key>>3)]) ----
        #pragma unroll
        for (int i = 0; i < 8; ++i) {
            int rv = __shfl(rl, i * 8 + (lane >> 3));
            int sc = (lane & 7) ^ i;
            load_lds16(&vbase[(size_t)rv * HD_ + sc * 8], Vlds + i * 512);
        }

        // ---- K A-frags: row=key-in-tile (m16), k=d chunk g*8 + 32s ----
        H8 ka[4][2];
        #pragma unroll
        for (int tt = 0; tt < 4; ++tt) {
            int rt = __shfl(rl, tt * 16 + m16);
            const unsigned short* kr = &kbase[(size_t)rt * HD_];
            ka[tt][0].u = *(const ushort8v*)(kr + g * 8);
            ka[tt][1].u = *(const ushort8v*)(kr + 32 + g * 8);
        }
        // ---- Q B-frags: col=m16 (own member row; Q pre-scaled by 0.125) ----
        const unsigned short* qr = &qbase[(size_t)mm * HD_];
        H8 qb0, qb1;
        qb0.u = *(const ushort8v*)(qr + g * 8);
        qb1.u = *(const ushort8v*)(qr + 32 + g * 8);

        // ---- scores: D[key=16t+4g+r][m=m16] ----
        float4v acc[4];
        #pragma unroll
        for (int tt = 0; tt < 4; ++tt) {
            #pragma unroll
            for (int r = 0; r < 4; ++r) acc[tt][r] = 0.f;
        }
        #pragma unroll
        for (int tt = 0; tt < 4; ++tt) {
            acc[tt] = __builtin_amdgcn_mfma_f32_16x16x32_f16(ka[tt][0].h, qb0.h, acc[tt], 0, 0, 0);
            acc[tt] = __builtin_amdgcn_mfma_f32_16x16x32_f16(ka[tt][1].h, qb1.h, acc[tt], 0, 0, 0);
        }

        // ---- softmax over 64 keys for this lane's m ----
        float mx = acc[0][0];
        #pragma unroll
        for (int tt = 0; tt < 4; ++tt)
            #pragma unroll
            for (int r = 0; r < 4; ++r) mx = fmaxf(mx, acc[tt][r]);
        mx = fmaxf(mx, __shfl_xor(mx, 16));
        mx = fmaxf(mx, __shfl_xor(mx, 32));
        float ew[4][4], su = 0.f;
        #pragma unroll
        for (int tt = 0; tt < 4; ++tt)
            #pragma unroll
            for (int r = 0; r < 4; ++r) { ew[tt][r] = __expf(acc[tt][r] - mx); su += ew[tt][r]; }
        su += __shfl_xor(su, 16);
        su += __shfl_xor(su, 32);
        const float rinv = __builtin_amdgcn_rcpf(su);

        unsigned int whu[4][2];
        #pragma unroll
        for (int tt = 0; tt < 4; ++tt) {
            whu[tt][0] = pkrtz(ew[tt][0] * rinv, ew[tt][1] * rinv);
            whu[tt][1] = pkrtz(ew[tt][2] * rinv, ew[tt][3] * rinv);
        }

        // ---- P redistribution: C-layout (key=16t+4g+r @ col m) ->
        // A-frag (row m=m16, k=key 32s+8g+j) ----
        const int A0 = (((g & 1) << 5) | m16) * 4;
        const int A1 = A0 + 64;
        const bool ghi = (g >> 1) != 0;
        H8 pa[2];
        #pragma unroll
        for (int s = 0; s < 2; ++s) {
            unsigned int l0a = (unsigned int)__builtin_amdgcn_ds_bpermute(A0, (int)whu[2 * s][0]);
            unsigned int l0b = (unsigned int)__builtin_amdgcn_ds_bpermute(A0, (int)whu[2 * s + 1][0]);
            unsigned int h0a = (unsigned int)__builtin_amdgcn_ds_bpermute(A0, (int)whu[2 * s][1]);
            unsigned int h0b = (unsigned int)__builtin_amdgcn_ds_bpermute(A0, (int)whu[2 * s + 1][1]);
            unsigned int l1a = (unsigned int)__builtin_amdgcn_ds_bpermute(A1, (int)whu[2 * s][0]);
            unsigned int l1b = (unsigned int)__builtin_amdgcn_ds_bpermute(A1, (int)whu[2 * s + 1][0]);
            unsigned int h1a = (unsigned int)__builtin_amdgcn_ds_bpermute(A1, (int)whu[2 * s][1]);
            unsigned int h1b = (unsigned int)__builtin_amdgcn_ds_bpermute(A1, (int)whu[2 * s + 1][1]);
            pa[s].w[0] = ghi ? l0b : l0a;
            pa[s].w[1] = ghi ? h0b : h0a;
            pa[s].w[2] = ghi ? l1b : l1a;
            pa[s].w[3] = ghi ? h1b : h1a;
        }

        // member rows for the store (D row m = g*4+r)
        int mr[4];
        #pragma unroll
        for (int r = 0; r < 4; ++r)
            mr[r] = __builtin_amdgcn_ds_bpermute((g * 4 + r) * 4, mm);

        // V DMA must have landed before the column reads
        asm volatile("s_waitcnt vmcnt(0)" ::: "memory");
        __builtin_amdgcn_sched_barrier(0);

        // ---- PV per 16-wide d-block: B col = d (m16), k = key ----
        #pragma unroll
        for (int dblk = 0; dblk < 4; ++dblk) {
            H8 vb[2];
            #pragma unroll
            for (int s = 0; s < 2; ++s) {
                const char* vp = (const char*)Vlds + (s * 32 + g * 8) * 128 +
                    (((dblk * 16 + m16) * 2) ^ ((((s * 4 + g) & 7)) << 4));
                #pragma unroll
                for (int j = 0; j < 8; ++j)
                    vb[s].u[j] = *(const unsigned short*)(vp + j * 128);
            }
            float4v o;
            o[0] = 0.f; o[1] = 0.f; o[2] = 0.f; o[3] = 0.f;
            o = __builtin_amdgcn_mfma_f32_16x16x32_f16(pa[0].h, vb[0].h, o, 0, 0, 0);
            o = __builtin_amdgcn_mfma_f32_16x16x32_f16(pa[1].h, vb[1].h, o, 0, 0, 0);
            #pragma unroll
            for (int r = 0; r < 4; ++r) {
                if (g * 4 + r < mcnt) {
                    size_t oi = ((size_t)b * S_ + mr[r]) * DIM_ + h * HD_ + dblk * 16 + m16;
                    Oh[oi] = f2h(o[r]);
                }
            }
        }
    }
}

// ---------------------------------------------------------------------------
// ws layout (bytes):
//   0    Q fp16 4MB | 8M K fp16 4MB | 16M V fp16 4MB
//   24M  attn out fp16 4MB
//   32M  Wqkv_h fp16 1.5M | +1.5M Wout_h fp16 0.5M
//   34M  members int[2048] | +8K recs int4[2048] | +40K nChunks
// ---------------------------------------------------------------------------
extern "C" void kernel_launch(void* const* d_in, const int* in_sizes, int n_in,
                              void* d_out, int out_size, void* d_ws, size_t ws_size,
                              hipStream_t stream)
{
    const float* x      = (const float*)d_in[0];
    const float* Wqkv   = (const float*)d_in[1];
    const float* bqkv   = (const float*)d_in[2];
    const float* Wout   = (const float*)d_in[3];
    const float* bout   = (const float*)d_in[4];
    const int*   routes = (const int*)d_in[5];
    float* out = (float*)d_out;

    char* w = (char*)d_ws;
    unsigned short* Qh = (unsigned short*)(w);
    unsigned short* Kh = (unsigned short*)(w + (8u << 20));
    unsigned short* Vh = (unsigned short*)(w + (16u << 20));
    unsigned short* ah = (unsigned short*)(w + (24u << 20));
    unsigned short* wqh = (unsigned short*)(w + (32u << 20));
    unsigned short* woh = (unsigned short*)(w + (32u << 20) + 1572864u);
    int*  members = (int*)(w + (34u << 20));
    int4* recs    = (int4*)(w + (34u << 20) + 8192u);
    int*  nchp    = (int*)(w + (34u << 20) + 8192u + 32768u);

    dim3 blk(256);

    // prep: W transposes (1024 blocks) + grouping (1 block, shfl-scan)
    prep_all<<<dim3(1025), blk, 0, stream>>>(Wqkv, wqh, Wout, woh,
                                             routes, members, recs, nchp);

    // qkv: M=4096, N=1536, K=512; BM=64 -> 1024 blocks = 4/CU (TLP for
    // barrier-drain overlap); A = x fp32 with fused conversion
    gemm_mfma<64, 96, 32, 48, true><<<dim3(NQKV_ / 96, M_ / 64), blk, 0, stream>>>(
        x, wqh, bqkv, nullptr, Qh, Kh, Vh, NQKV_, DIM_, 1);

    attn_kernel<<<dim3(2048), blk, 0, stream>>>(Qh, Kh, Vh, routes,
                                                members, recs, nchp, ah);

    // out-proj: M=4096, N=512, K=512; A = ah fp16 (gload_lds path)
    gemm_mfma<64, 64, 32, 32, false><<<dim3(DIM_ / 64, M_ / 64), blk, 0, stream>>>(
        ah, woh, bout, out, nullptr, nullptr, nullptr, DIM_, DIM_, 0);
}